// Round 1
// baseline (284.980 us; speedup 1.0000x reference)
//
#include <hip/hip_runtime.h>

// Problem constants (from reference): N0=N1=100000, K=16, D_MODEL=64, D_ATTN=32, H=4
// dh_attn=8, dh_val=16, scale = 1/sqrt(8)

// ---------------------------------------------------------------------------
// K0 = feats0 @ Wk[0:64] + bk   [N0, 32]
// V0 = feats0 @ Wv[0:64] + bv   [N0, 64]
// fused as a [64 rows x 96 cols] tile GEMM per block, 256 threads, 4x6 reg tile
// ---------------------------------------------------------------------------
__global__ __launch_bounds__(256) void kv0_kernel(
    const float* __restrict__ feats0,
    const float* __restrict__ Wk, const float* __restrict__ bk,
    const float* __restrict__ Wv, const float* __restrict__ bv,
    float* __restrict__ K0, float* __restrict__ V0, int n0)
{
    __shared__ float Xs[64][65];   // +1 pad: kill stride-64 bank conflicts
    __shared__ float Ws[64][96];
    __shared__ float bs[96];
    const int tid = threadIdx.x;
    const int rowBase = blockIdx.x * 64;

    for (int e = tid; e < 64 * 96; e += 256) {
        int kk = e / 96;
        int c  = e - kk * 96;
        Ws[kk][c] = (c < 32) ? Wk[kk * 32 + c] : Wv[kk * 64 + (c - 32)];
    }
    if (tid < 96) bs[tid] = (tid < 32) ? bk[tid] : bv[tid - 32];
    for (int e = tid; e < 64 * 64; e += 256) {
        int r = e >> 6, c = e & 63;
        int gr = rowBase + r;
        Xs[r][c] = (gr < n0) ? feats0[gr * 64 + c] : 0.0f;
    }
    __syncthreads();

    const int tc = tid & 15, tr = tid >> 4;
    const int c0 = tc * 6, r0 = tr * 4;
    float acc[4][6];
    #pragma unroll
    for (int i = 0; i < 4; i++)
        #pragma unroll
        for (int jj = 0; jj < 6; jj++)
            acc[i][jj] = bs[c0 + jj];

    #pragma unroll 4
    for (int kk = 0; kk < 64; kk++) {
        float x0 = Xs[r0 + 0][kk], x1 = Xs[r0 + 1][kk];
        float x2 = Xs[r0 + 2][kk], x3 = Xs[r0 + 3][kk];
        #pragma unroll
        for (int jj = 0; jj < 6; jj++) {
            float w = Ws[kk][c0 + jj];
            acc[0][jj] = fmaf(x0, w, acc[0][jj]);
            acc[1][jj] = fmaf(x1, w, acc[1][jj]);
            acc[2][jj] = fmaf(x2, w, acc[2][jj]);
            acc[3][jj] = fmaf(x3, w, acc[3][jj]);
        }
    }

    #pragma unroll
    for (int i = 0; i < 4; i++) {
        int gr = rowBase + r0 + i;
        if (gr < n0) {
            #pragma unroll
            for (int jj = 0; jj < 6; jj++) {
                int c = c0 + jj;
                if (c < 32) K0[gr * 32 + c] = acc[i][jj];
                else        V0[gr * 64 + (c - 32)] = acc[i][jj];
            }
        }
    }
}

// ---------------------------------------------------------------------------
// Q = feats1 @ Wq + bq   [N1, 32]; 64 rows x 32 cols per block, 2x4 reg tile
// ---------------------------------------------------------------------------
__global__ __launch_bounds__(256) void q_kernel(
    const float* __restrict__ feats1,
    const float* __restrict__ Wq, const float* __restrict__ bq,
    float* __restrict__ Q, int n1)
{
    __shared__ float Xs[64][65];
    __shared__ float Ws[64][32];
    __shared__ float bs[32];
    const int tid = threadIdx.x;
    const int rowBase = blockIdx.x * 64;

    for (int e = tid; e < 64 * 32; e += 256) {
        int kk = e >> 5, c = e & 31;
        Ws[kk][c] = Wq[kk * 32 + c];
    }
    if (tid < 32) bs[tid] = bq[tid];
    for (int e = tid; e < 64 * 64; e += 256) {
        int r = e >> 6, c = e & 63;
        int gr = rowBase + r;
        Xs[r][c] = (gr < n1) ? feats1[gr * 64 + c] : 0.0f;
    }
    __syncthreads();

    const int tc = tid & 7, tr = tid >> 3;   // 8 col groups x 32 row groups
    const int c0 = tc * 4, r0 = tr * 2;
    float acc[2][4];
    #pragma unroll
    for (int i = 0; i < 2; i++)
        #pragma unroll
        for (int jj = 0; jj < 4; jj++)
            acc[i][jj] = bs[c0 + jj];

    #pragma unroll 4
    for (int kk = 0; kk < 64; kk++) {
        float x0 = Xs[r0 + 0][kk], x1 = Xs[r0 + 1][kk];
        #pragma unroll
        for (int jj = 0; jj < 4; jj++) {
            float w = Ws[kk][c0 + jj];
            acc[0][jj] = fmaf(x0, w, acc[0][jj]);
            acc[1][jj] = fmaf(x1, w, acc[1][jj]);
        }
    }

    #pragma unroll
    for (int i = 0; i < 2; i++) {
        int gr = rowBase + r0 + i;
        if (gr < n1) {
            #pragma unroll
            for (int jj = 0; jj < 4; jj++)
                Q[gr * 32 + c0 + jj] = acc[i][jj];
        }
    }
}

// ---------------------------------------------------------------------------
// Main attention kernel: 16 lanes per point, 16 points per 256-thread block.
// Phase 1: lane j = neighbor j -> logits + softmax (shfl width 16).
// Phase 2: lane j = output dims [4j,4j+4) -> coalesced V0 row gather + combine.
// ---------------------------------------------------------------------------
__global__ __launch_bounds__(256) void attn_kernel(
    const float* __restrict__ coords0, const float* __restrict__ coords1,
    const int*   __restrict__ knn,
    const float* __restrict__ Q, const float* __restrict__ K0,
    const float* __restrict__ V0,
    const float* __restrict__ Wk, const float* __restrict__ Wv,
    float* __restrict__ out, float* __restrict__ outIdx, int n1)
{
    __shared__ __align__(16) float sWk3[3][32];       // Wk rows 64..66
    __shared__ __align__(16) float sWv3[3][64];       // Wv rows 64..66
    __shared__ float sAttn[16][4][17];                // +1 pad: conflict-free phase-2 read
    __shared__ float sRel[16][16][3];
    __shared__ int   sIdx[16][16];

    const int tid = threadIdx.x;
    if (tid < 96)  ((float*)sWk3)[tid] = Wk[64 * 32 + tid];   // rows 64..66 contiguous
    if (tid < 192) ((float*)sWv3)[tid] = Wv[64 * 64 + tid];
    __syncthreads();

    const int p = tid >> 4;          // local point 0..15
    const int j = tid & 15;          // lane within point
    const int n = blockIdx.x * 16 + p;
    const bool valid = (n < n1);
    const int nc = valid ? n : (n1 - 1);

    // ---- Phase 1: neighbor-parallel logits + softmax ----
    const int idx = knn[nc * 16 + j];
    const float c1x = coords1[nc * 3 + 0];
    const float c1y = coords1[nc * 3 + 1];
    const float c1z = coords1[nc * 3 + 2];
    const float r0 = coords0[idx * 3 + 0] - c1x;
    const float r1 = coords0[idx * 3 + 1] - c1y;
    const float r2 = coords0[idx * 3 + 2] - c1z;

    const float4* __restrict__ K04 = (const float4*)K0;
    const float4* __restrict__ Q4  = (const float4*)Q;
    const float4* __restrict__ Wa  = (const float4*)&sWk3[0][0];
    const float4* __restrict__ Wb  = (const float4*)&sWk3[1][0];
    const float4* __restrict__ Wc  = (const float4*)&sWk3[2][0];

    float logit[4] = {0.f, 0.f, 0.f, 0.f};
    #pragma unroll
    for (int dd = 0; dd < 8; dd++) {
        float4 k4 = K04[idx * 8 + dd];
        float4 wa = Wa[dd], wb = Wb[dd], wc = Wc[dd];
        k4.x += r0 * wa.x + r1 * wb.x + r2 * wc.x;
        k4.y += r0 * wa.y + r1 * wb.y + r2 * wc.y;
        k4.z += r0 * wa.z + r1 * wb.z + r2 * wc.z;
        k4.w += r0 * wa.w + r1 * wb.w + r2 * wc.w;
        float4 q4 = Q4[nc * 8 + dd];
        logit[dd >> 1] += q4.x * k4.x + q4.y * k4.y + q4.z * k4.z + q4.w * k4.w;
    }

    const float scale = 0.35355339059327373f;  // 1/sqrt(8)
    #pragma unroll
    for (int h = 0; h < 4; h++) {
        float l = logit[h] * scale;
        float m = l;
        m = fmaxf(m, __shfl_xor(m, 1, 16));
        m = fmaxf(m, __shfl_xor(m, 2, 16));
        m = fmaxf(m, __shfl_xor(m, 4, 16));
        m = fmaxf(m, __shfl_xor(m, 8, 16));
        float e = __expf(l - m);
        float s = e;
        s += __shfl_xor(s, 1, 16);
        s += __shfl_xor(s, 2, 16);
        s += __shfl_xor(s, 4, 16);
        s += __shfl_xor(s, 8, 16);
        sAttn[p][h][j] = e * __builtin_amdgcn_rcpf(s);
    }
    sRel[p][j][0] = r0; sRel[p][j][1] = r1; sRel[p][j][2] = r2;
    sIdx[p][j] = idx;

    if (valid) outIdx[n * 16 + j] = (float)idx;   // echo knn_idxs as float32

    __syncthreads();

    // ---- Phase 2: dim-parallel weighted sum of V0 rows ----
    const int hh = j >> 2;            // head owning dims [4j, 4j+4)
    const float4* __restrict__ V04 = (const float4*)V0;
    float4 acc = {0.f, 0.f, 0.f, 0.f};
    float rb0 = 0.f, rb1 = 0.f, rb2 = 0.f;

    #pragma unroll
    for (int jj = 0; jj < 16; jj++) {
        float a = sAttn[p][hh][jj];
        int iv = sIdx[p][jj];
        float4 v4 = V04[iv * 16 + j];   // 16 lanes read one contiguous 256B row
        acc.x = fmaf(a, v4.x, acc.x);
        acc.y = fmaf(a, v4.y, acc.y);
        acc.z = fmaf(a, v4.z, acc.z);
        acc.w = fmaf(a, v4.w, acc.w);
        rb0 = fmaf(a, sRel[p][jj][0], rb0);
        rb1 = fmaf(a, sRel[p][jj][1], rb1);
        rb2 = fmaf(a, sRel[p][jj][2], rb2);
    }

    // rbar @ Wv3 correction (valid because softmax weights sum to 1)
    const float4* __restrict__ Va = (const float4*)&sWv3[0][0];
    const float4* __restrict__ Vb = (const float4*)&sWv3[1][0];
    const float4* __restrict__ Vc = (const float4*)&sWv3[2][0];
    float4 wa = Va[j], wb = Vb[j], wc = Vc[j];
    acc.x += rb0 * wa.x + rb1 * wb.x + rb2 * wc.x;
    acc.y += rb0 * wa.y + rb1 * wb.y + rb2 * wc.y;
    acc.z += rb0 * wa.z + rb1 * wb.z + rb2 * wc.z;
    acc.w += rb0 * wa.w + rb1 * wb.w + rb2 * wc.w;

    if (valid) ((float4*)out)[n * 16 + j] = acc;
}

// ---------------------------------------------------------------------------
extern "C" void kernel_launch(void* const* d_in, const int* in_sizes, int n_in,
                              void* d_out, int out_size, void* d_ws, size_t ws_size,
                              hipStream_t stream) {
    const float* coords0 = (const float*)d_in[0];
    const float* coords1 = (const float*)d_in[1];
    const float* feats0  = (const float*)d_in[2];
    const float* feats1  = (const float*)d_in[3];
    const int*   knn     = (const int*)d_in[4];
    const float* Wq      = (const float*)d_in[5];
    const float* bq      = (const float*)d_in[6];
    const float* Wk      = (const float*)d_in[7];
    const float* bk      = (const float*)d_in[8];
    const float* Wv      = (const float*)d_in[9];
    const float* bv      = (const float*)d_in[10];

    const int n0 = in_sizes[0] / 3;
    const int n1 = in_sizes[1] / 3;

    float* K0 = (float*)d_ws;                       // [n0, 32]
    float* V0 = K0 + (size_t)n0 * 32;               // [n0, 64]
    float* Q  = V0 + (size_t)n0 * 64;               // [n1, 32]

    float* out    = (float*)d_out;                  // [n1, 64]
    float* outIdx = out + (size_t)n1 * 64;          // [1, n1, 16] as float

    kv0_kernel<<<(n0 + 63) / 64, 256, 0, stream>>>(feats0, Wk, bk, Wv, bv, K0, V0, n0);
    q_kernel  <<<(n1 + 63) / 64, 256, 0, stream>>>(feats1, Wq, bq, Q, n1);
    attn_kernel<<<(n1 + 15) / 16, 256, 0, stream>>>(coords0, coords1, knn,
                                                    Q, K0, V0, Wk, Wv,
                                                    out, outIdx, n1);
}

// Round 2
// 199.942 us; speedup vs baseline: 1.4253x; 1.4253x over previous
//
#include <hip/hip_runtime.h>

// N0=N1=100000, K=16, D_MODEL=64, D_ATTN=32, H=4, dh_attn=8, dh_val=16
// Strategy:
//   KV = feats0 @ [Wk[:64] | Wv[:64]] + [bk|bv]  -> f16 [n0][96]  (MFMA f16)
//   Q  = feats1 @ Wq + bq                        -> f32 [n1][32]  (MFMA f16)
//   attn: k_j = KV[idx].k + rel@Wk3 ; softmax ; out = sum a_j (KV[idx].v) + rbar@Wv3
//   (rel@Wv3 pulled out of the sum since softmax weights sum to 1)

using half8  = __attribute__((ext_vector_type(8))) _Float16;
using half4  = __attribute__((ext_vector_type(4))) _Float16;
using floatx4 = __attribute__((ext_vector_type(4))) float;

// ---------------------------------------------------------------------------
// Pre-swizzle W into MFMA B-fragment order, f16.
// B-frag layout (16x16x32): lane holds B[k = (lane>>4)*8 + j][n = lane&15],
// linear index ((t*2+h)*64+lane)*8+j, k = h*32 + (lane>>4)*8 + j, n = t*16+(lane&15)
// ---------------------------------------------------------------------------
__global__ __launch_bounds__(256) void frag_setup_kernel(
    const float* __restrict__ Wq, const float* __restrict__ Wk,
    const float* __restrict__ Wv,
    _Float16* __restrict__ fragKV, _Float16* __restrict__ fragQ)
{
    const int stride = blockDim.x * gridDim.x;
    for (int e = blockIdx.x * blockDim.x + threadIdx.x; e < 6 * 2 * 64 * 8; e += stride) {
        int j = e & 7, lane = (e >> 3) & 63, h = (e >> 9) & 1, t = e >> 10;
        int k = h * 32 + ((lane >> 4) * 8) + j;
        int n = t * 16 + (lane & 15);
        float v = (n < 32) ? Wk[k * 32 + n] : Wv[k * 64 + (n - 32)];
        fragKV[e] = (_Float16)v;
    }
    for (int e = blockIdx.x * blockDim.x + threadIdx.x; e < 2 * 2 * 64 * 8; e += stride) {
        int j = e & 7, lane = (e >> 3) & 63, h = (e >> 9) & 1, t = e >> 10;
        int k = h * 32 + ((lane >> 4) * 8) + j;
        int n = t * 16 + (lane & 15);
        fragQ[e] = (_Float16)Wq[k * 32 + n];
    }
}

// ---------------------------------------------------------------------------
// X[nrows,64] @ W[64,16*NT] + b -> out (f16 or f32). 4 waves/block, 16 rows/wave.
// A-frag: lane holds X[m0 + (lane&15)][k = (lane>>4)*8 + j] (two K=32 halves).
// C/D: col = lane&15, row = (lane>>4)*4 + reg.
// ---------------------------------------------------------------------------
template <int NT, bool F16OUT>
__global__ __launch_bounds__(256, 4) void proj_kernel(
    const float* __restrict__ X, const _Float16* __restrict__ frag,
    const float* __restrict__ bA, const float* __restrict__ bB, int split,
    void* __restrict__ outv, int nrows)
{
    const int tid  = threadIdx.x;
    const int wave = tid >> 6;
    const int lane = tid & 63;
    const int l15  = lane & 15;
    const int quad = lane >> 4;
    const int m0   = blockIdx.x * 64 + wave * 16;

    const int row  = m0 + l15;
    const int rowc = (row < nrows) ? row : 0;

    const floatx4* X4 = (const floatx4*)(X + (size_t)rowc * 64);
    floatx4 f0 = X4[quad * 2 + 0], f1 = X4[quad * 2 + 1];
    floatx4 f2 = X4[quad * 2 + 8], f3 = X4[quad * 2 + 9];

    half8 a0, a1;
    a0[0] = (_Float16)f0.x; a0[1] = (_Float16)f0.y; a0[2] = (_Float16)f0.z; a0[3] = (_Float16)f0.w;
    a0[4] = (_Float16)f1.x; a0[5] = (_Float16)f1.y; a0[6] = (_Float16)f1.z; a0[7] = (_Float16)f1.w;
    a1[0] = (_Float16)f2.x; a1[1] = (_Float16)f2.y; a1[2] = (_Float16)f2.z; a1[3] = (_Float16)f2.w;
    a1[4] = (_Float16)f3.x; a1[5] = (_Float16)f3.y; a1[6] = (_Float16)f3.z; a1[7] = (_Float16)f3.w;

    const half8* bf = (const half8*)frag;  // [NT][2][64] of half8

    floatx4 acc[NT];
    #pragma unroll
    for (int t = 0; t < NT; t++) {
        int n = t * 16 + l15;
        float bb = (n < split) ? bA[n] : bB[n - split];
        acc[t] = (floatx4){bb, bb, bb, bb};
    }
    #pragma unroll
    for (int t = 0; t < NT; t++) {
        acc[t] = __builtin_amdgcn_mfma_f32_16x16x32_f16(a0, bf[(t * 2 + 0) * 64 + lane], acc[t], 0, 0, 0);
        acc[t] = __builtin_amdgcn_mfma_f32_16x16x32_f16(a1, bf[(t * 2 + 1) * 64 + lane], acc[t], 0, 0, 0);
    }

    const int NCOL = NT * 16;
    #pragma unroll
    for (int t = 0; t < NT; t++) {
        #pragma unroll
        for (int r = 0; r < 4; r++) {
            int ro = m0 + quad * 4 + r;
            if (ro < nrows) {
                if (F16OUT) ((_Float16*)outv)[(size_t)ro * NCOL + t * 16 + l15] = (_Float16)acc[t][r];
                else        ((float*)outv)   [(size_t)ro * NCOL + t * 16 + l15] = acc[t][r];
            }
        }
    }
}

// ---------------------------------------------------------------------------
// Main attention: 16 lanes/point, 16 points/block.
// Phase 1: lane j = neighbor j -> logits + softmax (shfl width 16).
// Phase 2: lane j = output dims [4j,4j+4) -> coalesced f16 V row gather.
// ---------------------------------------------------------------------------
__global__ __launch_bounds__(256, 4) void attn_kernel(
    const float* __restrict__ coords0, const float* __restrict__ coords1,
    const int*   __restrict__ knn,
    const float* __restrict__ Qf, const _Float16* __restrict__ KVh,
    const float* __restrict__ Wk, const float* __restrict__ Wv,
    float* __restrict__ out, float* __restrict__ outIdx, int n1)
{
    __shared__ float sWk3[3][32];          // Wk rows 64..66
    __shared__ __align__(16) float sWv3[3][64];  // Wv rows 64..66
    __shared__ __align__(16) float sAttn[16][68]; // [p][h*16+j], stride 68: f4-aligned, banks spread
    __shared__ float sRel[16][16][3];
    __shared__ int   sIdx[16][16];

    const int tid = threadIdx.x;
    if (tid < 96)  ((float*)sWk3)[tid] = Wk[64 * 32 + tid];
    if (tid < 192) ((float*)sWv3)[tid] = Wv[64 * 64 + tid];
    __syncthreads();

    const int p = tid >> 4;
    const int j = tid & 15;
    const int n = blockIdx.x * 16 + p;
    const bool valid = (n < n1);
    const int nc = valid ? n : (n1 - 1);

    // ---- Phase 1 ----
    const int idx = knn[nc * 16 + j];
    const float c1x = coords1[nc * 3 + 0];
    const float c1y = coords1[nc * 3 + 1];
    const float c1z = coords1[nc * 3 + 2];
    const float r0 = coords0[idx * 3 + 0] - c1x;
    const float r1 = coords0[idx * 3 + 1] - c1y;
    const float r2 = coords0[idx * 3 + 2] - c1z;

    const half8*   kr = (const half8*)(KVh + (size_t)idx * 96);   // first 32 f16 = K row
    const floatx4* qr = (const floatx4*)(Qf + (size_t)nc * 32);

    float logit[4];
    #pragma unroll
    for (int h = 0; h < 4; h++) {
        half8 k8 = kr[h];
        floatx4 q0 = qr[h * 2 + 0], q1 = qr[h * 2 + 1];
        float qv[8] = {q0.x, q0.y, q0.z, q0.w, q1.x, q1.y, q1.z, q1.w};
        float acc = 0.f;
        #pragma unroll
        for (int i = 0; i < 8; i++) {
            int d = h * 8 + i;
            float kk = fmaf(r0, sWk3[0][d],
                       fmaf(r1, sWk3[1][d],
                       fmaf(r2, sWk3[2][d], (float)k8[i])));
            acc = fmaf(qv[i], kk, acc);
        }
        logit[h] = acc;
    }

    const float scale = 0.35355339059327373f;  // 1/sqrt(8)
    #pragma unroll
    for (int h = 0; h < 4; h++) {
        float l = logit[h] * scale;
        float m = l;
        m = fmaxf(m, __shfl_xor(m, 1, 16));
        m = fmaxf(m, __shfl_xor(m, 2, 16));
        m = fmaxf(m, __shfl_xor(m, 4, 16));
        m = fmaxf(m, __shfl_xor(m, 8, 16));
        float e = __expf(l - m);
        float s = e;
        s += __shfl_xor(s, 1, 16);
        s += __shfl_xor(s, 2, 16);
        s += __shfl_xor(s, 4, 16);
        s += __shfl_xor(s, 8, 16);
        sAttn[p][h * 16 + j] = e * __builtin_amdgcn_rcpf(s);
    }
    sRel[p][j][0] = r0; sRel[p][j][1] = r1; sRel[p][j][2] = r2;
    sIdx[p][j] = idx;

    if (valid) outIdx[n * 16 + j] = (float)idx;

    __syncthreads();

    // ---- Phase 2 ----
    const int hh = j >> 2;
    float a_[16];
    int   iv_[16];
    #pragma unroll
    for (int t = 0; t < 4; t++) {
        ((floatx4*)a_)[t] = ((const floatx4*)&sAttn[p][hh * 16])[t];  // broadcast
        ((int4*)iv_)[t]   = ((const int4*)&sIdx[p][0])[t];            // broadcast
    }

    floatx4 accA = {0.f, 0.f, 0.f, 0.f}, accB = {0.f, 0.f, 0.f, 0.f};
    float rb0 = 0.f, rb1 = 0.f, rb2 = 0.f;
    #pragma unroll
    for (int jj = 0; jj < 16; jj += 2) {
        half4 v0 = *(const half4*)(KVh + (size_t)iv_[jj]     * 96 + 32 + j * 4);
        half4 v1 = *(const half4*)(KVh + (size_t)iv_[jj + 1] * 96 + 32 + j * 4);
        float aA = a_[jj], aB = a_[jj + 1];
        accA.x = fmaf(aA, (float)v0[0], accA.x);
        accA.y = fmaf(aA, (float)v0[1], accA.y);
        accA.z = fmaf(aA, (float)v0[2], accA.z);
        accA.w = fmaf(aA, (float)v0[3], accA.w);
        accB.x = fmaf(aB, (float)v1[0], accB.x);
        accB.y = fmaf(aB, (float)v1[1], accB.y);
        accB.z = fmaf(aB, (float)v1[2], accB.z);
        accB.w = fmaf(aB, (float)v1[3], accB.w);
        rb0 = fmaf(aA, sRel[p][jj][0], rb0); rb0 = fmaf(aB, sRel[p][jj + 1][0], rb0);
        rb1 = fmaf(aA, sRel[p][jj][1], rb1); rb1 = fmaf(aB, sRel[p][jj + 1][1], rb1);
        rb2 = fmaf(aA, sRel[p][jj][2], rb2); rb2 = fmaf(aB, sRel[p][jj + 1][2], rb2);
    }

    floatx4 wa = ((const floatx4*)&sWv3[0][0])[j];
    floatx4 wb = ((const floatx4*)&sWv3[1][0])[j];
    floatx4 wc = ((const floatx4*)&sWv3[2][0])[j];
    floatx4 acc;
    acc.x = accA.x + accB.x + rb0 * wa.x + rb1 * wb.x + rb2 * wc.x;
    acc.y = accA.y + accB.y + rb0 * wa.y + rb1 * wb.y + rb2 * wc.y;
    acc.z = accA.z + accB.z + rb0 * wa.z + rb1 * wb.z + rb2 * wc.z;
    acc.w = accA.w + accB.w + rb0 * wa.w + rb1 * wb.w + rb2 * wc.w;

    if (valid) ((floatx4*)out)[n * 16 + j] = acc;
}

// ---------------------------------------------------------------------------
extern "C" void kernel_launch(void* const* d_in, const int* in_sizes, int n_in,
                              void* d_out, int out_size, void* d_ws, size_t ws_size,
                              hipStream_t stream) {
    const float* coords0 = (const float*)d_in[0];
    const float* coords1 = (const float*)d_in[1];
    const float* feats0  = (const float*)d_in[2];
    const float* feats1  = (const float*)d_in[3];
    const int*   knn     = (const int*)d_in[4];
    const float* Wq      = (const float*)d_in[5];
    const float* bq      = (const float*)d_in[6];
    const float* Wk      = (const float*)d_in[7];
    const float* bk      = (const float*)d_in[8];
    const float* Wv      = (const float*)d_in[9];
    const float* bv      = (const float*)d_in[10];

    const int n0 = in_sizes[0] / 3;
    const int n1 = in_sizes[1] / 3;

    // d_ws layout (bytes)
    char* ws = (char*)d_ws;
    _Float16* fragKV = (_Float16*)(ws + 0);            // 12288 B
    _Float16* fragQ  = (_Float16*)(ws + 16384);        // 4096 B
    _Float16* KVh    = (_Float16*)(ws + 32768);        // n0*96*2 B
    float*    Qf     = (float*)(ws + 32768 + (size_t)n0 * 96 * 2 + 64);  // n1*32*4 B
    // fix alignment of Qf to 16B
    Qf = (float*)(((size_t)Qf + 15) & ~(size_t)15);

    float* out    = (float*)d_out;              // [n1,64]
    float* outIdx = out + (size_t)n1 * 64;      // [1,n1,16] as float

    frag_setup_kernel<<<16, 256, 0, stream>>>(Wq, Wk, Wv, fragKV, fragQ);
    proj_kernel<6, true ><<<(n0 + 63) / 64, 256, 0, stream>>>(feats0, fragKV, bk, bv, 32, (void*)KVh, n0);
    proj_kernel<2, false><<<(n1 + 63) / 64, 256, 0, stream>>>(feats1, fragQ, bq, bq, 999, (void*)Qf, n1);
    attn_kernel<<<(n1 + 15) / 16, 256, 0, stream>>>(coords0, coords1, knn,
                                                    Qf, KVh, Wk, Wv, out, outIdx, n1);
}